// Round 11
// baseline (340.430 us; speedup 1.0000x reference)
//
#include <hip/hip_runtime.h>
#include <math.h>

typedef short v4s __attribute__((ext_vector_type(4)));
typedef short v8s __attribute__((ext_vector_type(8)));
typedef float v4f __attribute__((ext_vector_type(4)));

#define L2E 1.4426950408889634f
#define INV_SCALE 0.08838834764831845f       // 1/sqrt(128)
#define SCL2 (INV_SCALE * L2E)               // folded scale for exp2

static __device__ __forceinline__ short f2bf(float x) {
    union { float f; unsigned u; } c; c.f = x;
    unsigned u = c.u;
    unsigned r = (u + 0x7fffu + ((u >> 16) & 1u)) >> 16;  // RNE
    return (short)r;
}

// ---- P0 fused (verbatim R8/R9, verified): 512 blocks. isel=0: ctx gemm->Qa.
// isel=1: qry gemm->Ka PLUS fused qry transpose->VaT + maskadd. VaT written
// with chunk-XOR swizzle (granule j of row d at position j^(d&7)).
__global__ __launch_bounds__(256) void k_pre(const float* __restrict__ ctx,
                                             const float* __restrict__ qry,
                                             const float* __restrict__ Win,
                                             const float* __restrict__ Wmem,
                                             const int* __restrict__ qmask,
                                             short* __restrict__ Qa,
                                             short* __restrict__ Ka,
                                             short* __restrict__ VaT,
                                             float* __restrict__ maskadd) {
    __shared__ __align__(16) short WtS[128 * 132];      // 33792 B
    __shared__ __align__(16) short Tt[256 * 72];        // 36864 B ([k][row64+pad])
    int x = blockIdx.x;
    int tid = threadIdx.x;
    int msel = x & 255, isel = x >> 8;
    const float* X = isel ? qry : ctx;
    const float* W = isel ? Wmem : Win;
    short* Y = isel ? Ka : Qa;

    int w = tid >> 6, lane = tid & 63;
    int ln = lane & 15, qd = lane >> 4;
    int m0 = msel * 64 + w * 16;
    v4f zero = {0.f, 0.f, 0.f, 0.f};
    v4f o[8];
#pragma unroll
    for (int i = 0; i < 8; ++i) o[i] = zero;

#pragma unroll 1
    for (int kh = 0; kh < 2; ++kh) {
        if (kh) __syncthreads();                        // protect WtS reuse
#pragma unroll 8
        for (int i = 0; i < 64; ++i) {
            int id = i * 256 + tid;
            int k = id >> 7, fp = id & 127;
            WtS[fp * 132 + k] = f2bf(W[(kh * 128 + k) * 128 + fp]);
        }
        __syncthreads();
#pragma unroll
        for (int kk = 0; kk < 4; ++kk) {
            const float* xp = X + (size_t)(m0 + ln) * 256 + kh * 128 + kk * 32 + qd * 8;
            float4 x0 = *(const float4*)xp;
            float4 x1 = *(const float4*)(xp + 4);
            v8s a;
            a[0] = f2bf(x0.x); a[1] = f2bf(x0.y); a[2] = f2bf(x0.z); a[3] = f2bf(x0.w);
            a[4] = f2bf(x1.x); a[5] = f2bf(x1.y); a[6] = f2bf(x1.z); a[7] = f2bf(x1.w);
            if (isel) {                                  // fused transpose staging
#pragma unroll
                for (int si = 0; si < 8; ++si)
                    Tt[(kh * 128 + kk * 32 + qd * 8 + si) * 72 + (w * 16 + ln)] = a[si];
            }
#pragma unroll
            for (int nt = 0; nt < 8; ++nt) {
                v8s bfr = *(const v8s*)(WtS + (nt * 16 + ln) * 132 + kk * 32 + qd * 8);
                o[nt] = __builtin_amdgcn_mfma_f32_16x16x32_bf16(a, bfr, o[nt], 0, 0, 0);
            }
        }
    }
#pragma unroll
    for (int nt = 0; nt < 8; ++nt) {
#pragma unroll
        for (int r = 0; r < 4; ++r) {
            float v = o[nt][r];
            v = v > 0.f ? v : 0.01f * (__expf(v) - 1.f);
            Y[(size_t)(m0 + qd * 4 + r) * 128 + nt * 16 + ln] = f2bf(v);
        }
    }

    if (isel) {
        __syncthreads();                                 // Tt complete
        int b2 = msel >> 5, q0 = (msel & 31) * 64;
        int dr = tid >> 3, j = tid & 7;
#pragma unroll
        for (int i = 0; i < 8; ++i) {
            int d = dr + i * 32;
            v8s vv = *(const v8s*)(Tt + d * 72 + j * 8);
            *(v8s*)(VaT + ((size_t)(b2 * 256 + d)) * 2048 + q0 + ((j ^ (d & 7)) << 3)) = vv;
        }
        if (tid < 64) {
            int qq = b2 * 2048 + q0 + tid;
            maskadd[qq] = (qmask[qq] > 0) ? 0.f : -__builtin_inff();
        }
    }
}

// ------------- flash attention: 4-way in-block kv-split, 16 waves ---------
// (verbatim R10 except __launch_bounds__(1024, 1): hipcc's 2nd arg is min
// BLOCKS/CU (CUDA semantics) -- R10's (1024,4) requested 64 waves/CU,
// clamped to 32 -> VGPR capped at 64 -> 1 GB accumulator spill. (1024,1)
// -> 16 waves/CU -> cap 128 VGPR = the body's measured footprint, no spill.)
// 256 blocks x 1024 thr = 16 waves/CU = 4 waves/SIMD. Group g=w>>2 owns
// kv quarter [g*512,+512) = 8 steps of 64 kv. K/mask reg-prefetch 1 step
// ahead; V fragments direct from L2 (issued pre-barrier); P dbuf in LDS ->
// ONE s_barrier+lgkmcnt(0) per step. Zero traffic duplication vs R9.
// Epilogue: tree merge g1->OSa,g3->OSb; g0+=OSa,g2+=OSb; g2->OSa; g0 writes.
__global__ __launch_bounds__(1024, 1) void k_attn(const short* __restrict__ Qa,
                                                  const short* __restrict__ Ka,
                                                  const short* __restrict__ VaT,
                                                  const float* __restrict__ maskadd,
                                                  float* __restrict__ out) {
    // 137216 B union:
    //   loop:     PS  [4 grp][2 buf][64 c][64 kv] shorts = 64 KB (at 0)
    //   epilogue: OSa [64][260] f32 (at 0), OSb (at 66560), lS (at 133120)
    __shared__ __align__(16) char smem[137216];
    short* PSbase = (short*)smem;
    float* OSa = (float*)smem;
    float* OSb = (float*)(smem + 66560);
    float* lS  = (float*)(smem + 133120);    // [16 waves][64 c]

    const int STEPS = 8;
    int blk = blockIdx.x;
    int b = blk & 7;
    int c0 = (blk >> 3) * 64;

    int tid = threadIdx.x;
    int w = tid >> 6, lane = tid & 63, ln = lane & 15, qd = lane >> 4;
    int g = w >> 2, wl = w & 3;              // kv-quarter group, wave-in-group
    int kv0 = g * 512;
    short* PSg = PSbase + g * 8192;          // 2 buffers x 4096 shorts

    const short* qbase = Qa + (size_t)(b * 2048) * 128;
    const short* kbase = Ka + (size_t)(b * 2048 + kv0 + wl * 16 + ln) * 128 + qd * 8;
    const short* vbase = VaT + (size_t)(b * 256) * 2048;
    const float* mbase = maskadd + b * 2048 + kv0 + wl * 16 + qd * 4;

    // Q fragments for all 4 c-tiles (B-operand layout), resident
    v8s qf[4][4];
#pragma unroll
    for (int ct = 0; ct < 4; ++ct) {
        const short* qp = qbase + (size_t)(c0 + ct * 16 + ln) * 128 + qd * 8;
#pragma unroll
        for (int kk = 0; kk < 4; ++kk) qf[ct][kk] = *(const v8s*)(qp + kk * 32);
    }

    v4f zero = {0.f, 0.f, 0.f, 0.f};
    v4f o[4][4];                            // [ct][dt]; d = wl*64+dt*16+ln
#pragma unroll
    for (int i = 0; i < 4; ++i)
#pragma unroll
        for (int j = 0; j < 4; ++j) o[i][j] = zero;
    float lacc[4] = {0.f, 0.f, 0.f, 0.f};

    // ---- prologue: kf(0)+mask(0) ----
    v8s kfA[4], kfB[4];
    float4 mkA, mkB;
#pragma unroll
    for (int kk = 0; kk < 4; ++kk) kfA[kk] = *(const v8s*)(kbase + kk * 32);
    mkA = *(const float4*)(mbase);

#define ATT_STEP(IT, KFC, MKC, KFN, MKN) do {                                  \
    int q0 = kv0 + (IT) * 64;                                                  \
    int itn = ((IT) + 1) & (STEPS - 1);                                        \
    {   /* prefetch NEXT step's K frags + mask into regs (5 VMEM) */           \
        const short* kp = kbase + (size_t)itn * 8192;                          \
        _Pragma("unroll")                                                      \
        for (int kk = 0; kk < 4; ++kk) KFN[kk] = *(const v8s*)(kp + kk * 32);  \
        MKN = *(const float4*)(mbase + itn * 64);                              \
    }                                                                          \
    short* PSc = PSg + ((IT) & 1) * 4096;                                      \
    int kvb = q0 + wl * 16 + qd * 4;                                           \
    _Pragma("unroll")                                                          \
    for (int ct = 0; ct < 4; ++ct) {                                           \
        v4f s = zero;                                                          \
        _Pragma("unroll")                                                      \
        for (int kk = 0; kk < 4; ++kk)                                         \
            s = __builtin_amdgcn_mfma_f32_16x16x32_bf16(KFC[kk], qf[ct][kk],   \
                                                        s, 0, 0, 0);           \
        int cg = c0 + ct * 16 + ln;                                            \
        v4s pw;                                                                \
        float ls = 0.f;                                                        \
        _Pragma("unroll")                                                      \
        for (int r = 0; r < 4; ++r) {                                          \
            float v = s[r] * SCL2 + (&MKC.x)[r];                               \
            if (kvb + r == cg) v = -__builtin_inff();                          \
            float p = exp2f(v);                                                \
            ls += p;                                                           \
            pw[r] = f2bf(p);                                                   \
        }                                                                      \
        lacc[ct] += ls;                                                        \
        int hs = ((wl * 2 + (qd >> 1)) ^ (ln & 7));                            \
        *(v4s*)(PSc + (ct * 16 + ln) * 64 + hs * 8 + (qd & 1) * 4) = pw;       \
    }                                                                          \
    /* V fragments direct from L2 (issued pre-barrier: latency hides) */       \
    v8s vf2[2][4];                                                             \
    {                                                                          \
        const short* vp = vbase + q0;                                          \
        _Pragma("unroll")                                                      \
        for (int kk2 = 0; kk2 < 2; ++kk2) {                                    \
            int xg = ((kk2 * 4 + qd) ^ (ln & 7)) << 3;                         \
            _Pragma("unroll")                                                  \
            for (int dt = 0; dt < 4; ++dt)                                     \
                vf2[kk2][dt] = *(const v8s*)(vp +                              \
                    (size_t)(wl * 64 + dt * 16 + ln) * 2048 + xg);             \
        }                                                                      \
    }                                                                          \
    asm volatile("s_waitcnt lgkmcnt(0)" ::: "memory");                         \
    __builtin_amdgcn_s_barrier();           /* P visible; WAR for IT-1 buf */  \
    __builtin_amdgcn_s_setprio(1);                                             \
    _Pragma("unroll")                                                          \
    for (int kk2 = 0; kk2 < 2; ++kk2) {                                        \
        v8s pf[4];                                                             \
        _Pragma("unroll")                                                      \
        for (int ct = 0; ct < 4; ++ct)                                         \
            pf[ct] = *(const v8s*)(PSc + (ct * 16 + ln) * 64 +                 \
                                   (((kk2 * 4 + qd) ^ (ln & 7)) << 3));        \
        _Pragma("unroll")                                                      \
        for (int ct = 0; ct < 4; ++ct)                                         \
            _Pragma("unroll")                                                  \
            for (int dt = 0; dt < 4; ++dt)                                     \
                o[ct][dt] = __builtin_amdgcn_mfma_f32_16x16x32_bf16(           \
                    pf[ct], vf2[kk2][dt], o[ct][dt], 0, 0, 0);                 \
    }                                                                          \
    __builtin_amdgcn_s_setprio(0);                                             \
} while (0)

#pragma unroll 1
    for (int it2 = 0; it2 < STEPS; it2 += 2) {
        ATT_STEP(it2, kfA, mkA, kfB, mkB);
        ATT_STEP(it2 + 1, kfB, mkB, kfA, mkA);
    }
#undef ATT_STEP

    // ---- epilogue: tree-merge the 4 kv-quarters ----
    __syncthreads();                         // PS dead; smem becomes OS/lS

    // l: reduce over qd in-wave, publish per-wave sums
#pragma unroll
    for (int ct = 0; ct < 4; ++ct) {
        float v = lacc[ct];
        v += __shfl_xor(v, 16);
        v += __shfl_xor(v, 32);
        if (qd == 0) lS[w * 64 + ct * 16 + ln] = v;
    }

    // level 1: g1 -> OSa, g3 -> OSb  ([64 c][260 d-pad] f32 each)
    if (g == 1 || g == 3) {
        float* OS = (g == 1) ? OSa : OSb;
#pragma unroll
        for (int ct = 0; ct < 4; ++ct)
#pragma unroll
            for (int r = 0; r < 4; ++r)
#pragma unroll
                for (int dt = 0; dt < 4; ++dt)
                    OS[(ct * 16 + qd * 4 + r) * 260 + wl * 64 + dt * 16 + ln] =
                        o[ct][dt][r];
    }
    __syncthreads();

    // level 2: g0 += OSa, g2 += OSb (into registers)
    if (g == 0 || g == 2) {
        float* OS = (g == 0) ? OSa : OSb;
#pragma unroll
        for (int ct = 0; ct < 4; ++ct)
#pragma unroll
            for (int r = 0; r < 4; ++r)
#pragma unroll
                for (int dt = 0; dt < 4; ++dt)
                    o[ct][dt][r] += OS[(ct * 16 + qd * 4 + r) * 260 + wl * 64 + dt * 16 + ln];
    }
    __syncthreads();

    // level 3: g2 -> OSa
    if (g == 2) {
#pragma unroll
        for (int ct = 0; ct < 4; ++ct)
#pragma unroll
            for (int r = 0; r < 4; ++r)
#pragma unroll
                for (int dt = 0; dt < 4; ++dt)
                    OSa[(ct * 16 + qd * 4 + r) * 260 + wl * 64 + dt * 16 + ln] =
                        o[ct][dt][r];
    }
    __syncthreads();

    // final: g0 merges, normalizes, writes
    if (g == 0) {
#pragma unroll
        for (int ct = 0; ct < 4; ++ct) {
            float lv[4];
#pragma unroll
            for (int r = 0; r < 4; ++r) {
                float s = 0.f;
#pragma unroll
                for (int wv = 0; wv < 16; ++wv)
                    s += lS[wv * 64 + ct * 16 + qd * 4 + r];
                lv[r] = s;
            }
            int rowg = b * 2048 + c0 + ct * 16 + qd * 4;
#pragma unroll
            for (int r = 0; r < 4; ++r) {
                float inv = 1.f / lv[r];
#pragma unroll
                for (int dt = 0; dt < 4; ++dt) {
                    int col = wl * 64 + dt * 16 + ln;
                    float sum = o[ct][dt][r] +
                                OSa[(ct * 16 + qd * 4 + r) * 260 + col];
                    out[(size_t)(rowg + r) * 256 + col] = sum * inv;
                }
            }
        }
    }
}

extern "C" void kernel_launch(void* const* d_in, const int* in_sizes, int n_in,
                              void* d_out, int out_size, void* d_ws, size_t ws_size,
                              hipStream_t stream) {
    const float* ctx  = (const float*)d_in[0];
    const float* qry  = (const float*)d_in[1];
    const float* win  = (const float*)d_in[2];
    const float* wmem = (const float*)d_in[3];
    const int* qmask  = (const int*)d_in[4];
    float* out = (float*)d_out;

    char* ws = (char*)d_ws;
    short* Qa      = (short*)(ws);                          // 4 MB
    short* Ka      = (short*)(ws + (4u << 20));             // 4 MB
    short* VaT     = (short*)(ws + (8u << 20));             // 8 MB (chunk-XOR swizzled)
    float* maskadd = (float*)(ws + (16u << 20));            // 64 KB

    k_pre<<<dim3(512), 256, 0, stream>>>(ctx, qry, win, wmem, qmask,
                                         Qa, Ka, VaT, maskadd);
    k_attn<<<dim3(256), 1024, 0, stream>>>(Qa, Ka, VaT, maskadd, out);
}

// Round 12
// 163.619 us; speedup vs baseline: 2.0806x; 2.0806x over previous
//
#include <hip/hip_runtime.h>
#include <math.h>

typedef short v4s __attribute__((ext_vector_type(4)));
typedef short v8s __attribute__((ext_vector_type(8)));
typedef float v4f __attribute__((ext_vector_type(4)));

#define L2E 1.4426950408889634f
#define INV_SCALE 0.08838834764831845f       // 1/sqrt(128)
#define SCL2 (INV_SCALE * L2E)               // folded scale for exp2

static __device__ __forceinline__ short f2bf(float x) {
    union { float f; unsigned u; } c; c.f = x;
    unsigned u = c.u;
    unsigned r = (u + 0x7fffu + ((u >> 16) & 1u)) >> 16;  // RNE
    return (short)r;
}

// ---- P0 fused (verbatim R8/R9, verified): 512 blocks. isel=0: ctx gemm->Qa.
// isel=1: qry gemm->Ka PLUS fused qry transpose->VaT + maskadd. VaT written
// with chunk-XOR swizzle (granule j of row d at position j^(d&7)).
__global__ __launch_bounds__(256) void k_pre(const float* __restrict__ ctx,
                                             const float* __restrict__ qry,
                                             const float* __restrict__ Win,
                                             const float* __restrict__ Wmem,
                                             const int* __restrict__ qmask,
                                             short* __restrict__ Qa,
                                             short* __restrict__ Ka,
                                             short* __restrict__ VaT,
                                             float* __restrict__ maskadd) {
    __shared__ __align__(16) short WtS[128 * 132];      // 33792 B
    __shared__ __align__(16) short Tt[256 * 72];        // 36864 B ([k][row64+pad])
    int x = blockIdx.x;
    int tid = threadIdx.x;
    int msel = x & 255, isel = x >> 8;
    const float* X = isel ? qry : ctx;
    const float* W = isel ? Wmem : Win;
    short* Y = isel ? Ka : Qa;

    int w = tid >> 6, lane = tid & 63;
    int ln = lane & 15, qd = lane >> 4;
    int m0 = msel * 64 + w * 16;
    v4f zero = {0.f, 0.f, 0.f, 0.f};
    v4f o[8];
#pragma unroll
    for (int i = 0; i < 8; ++i) o[i] = zero;

#pragma unroll 1
    for (int kh = 0; kh < 2; ++kh) {
        if (kh) __syncthreads();                        // protect WtS reuse
#pragma unroll 8
        for (int i = 0; i < 64; ++i) {
            int id = i * 256 + tid;
            int k = id >> 7, fp = id & 127;
            WtS[fp * 132 + k] = f2bf(W[(kh * 128 + k) * 128 + fp]);
        }
        __syncthreads();
#pragma unroll
        for (int kk = 0; kk < 4; ++kk) {
            const float* xp = X + (size_t)(m0 + ln) * 256 + kh * 128 + kk * 32 + qd * 8;
            float4 x0 = *(const float4*)xp;
            float4 x1 = *(const float4*)(xp + 4);
            v8s a;
            a[0] = f2bf(x0.x); a[1] = f2bf(x0.y); a[2] = f2bf(x0.z); a[3] = f2bf(x0.w);
            a[4] = f2bf(x1.x); a[5] = f2bf(x1.y); a[6] = f2bf(x1.z); a[7] = f2bf(x1.w);
            if (isel) {                                  // fused transpose staging
#pragma unroll
                for (int si = 0; si < 8; ++si)
                    Tt[(kh * 128 + kk * 32 + qd * 8 + si) * 72 + (w * 16 + ln)] = a[si];
            }
#pragma unroll
            for (int nt = 0; nt < 8; ++nt) {
                v8s bfr = *(const v8s*)(WtS + (nt * 16 + ln) * 132 + kk * 32 + qd * 8);
                o[nt] = __builtin_amdgcn_mfma_f32_16x16x32_bf16(a, bfr, o[nt], 0, 0, 0);
            }
        }
    }
#pragma unroll
    for (int nt = 0; nt < 8; ++nt) {
#pragma unroll
        for (int r = 0; r < 4; ++r) {
            float v = o[nt][r];
            v = v > 0.f ? v : 0.01f * (__expf(v) - 1.f);
            Y[(size_t)(m0 + qd * 4 + r) * 128 + nt * 16 + ln] = f2bf(v);
        }
    }

    if (isel) {
        __syncthreads();                                 // Tt complete
        int b2 = msel >> 5, q0 = (msel & 31) * 64;
        int dr = tid >> 3, j = tid & 7;
#pragma unroll
        for (int i = 0; i < 8; ++i) {
            int d = dr + i * 32;
            v8s vv = *(const v8s*)(Tt + d * 72 + j * 8);
            *(v8s*)(VaT + ((size_t)(b2 * 256 + d)) * 2048 + q0 + ((j ^ (d & 7)) << 3)) = vv;
        }
        if (tid < 64) {
            int qq = b2 * 2048 + q0 + tid;
            maskadd[qq] = (qmask[qq] > 0) ? 0.f : -__builtin_inff();
        }
    }
}

// ------------- flash attention: c=32 tiles, 2 blocks/CU = 4 waves/SIMD ----
// R10/R11 lesson: 1024-thread blocks get VGPR-capped at 64 on this
// toolchain (both launch-bounds variants) -> 1 GB spill. Route around it:
// 512 blocks x 512 thr (proven 128-VGPR compile) = 2 INDEPENDENT blocks/CU
// = 16 waves/CU = 4 waves/SIMD. c-tile halved to 32 rows (ct loop = 2);
// in-block 2-way kv-split kept (2 groups x 4 waves, 16 steps of 64 kv).
// Per-step schedule is R9's verified body: K/mask reg-prefetch 1 step
// ahead; V fragments direct from L2 (issued pre-barrier); P dbuf in LDS ->
// ONE s_barrier+lgkmcnt(0) per step. Co-resident block pairs are
// barrier-independent -> one block's MFMA fills the other's stalls.
__global__ __launch_bounds__(512, 2) void k_attn(const short* __restrict__ Qa,
                                                 const short* __restrict__ Ka,
                                                 const short* __restrict__ VaT,
                                                 const float* __restrict__ maskadd,
                                                 float* __restrict__ out) {
    // 34304 B union:
    //   loop:     PS [2 grp][2 buf][32 c][64 kv] shorts = 16 KB (at 0)
    //   epilogue: OS [32][260] f32 (at 0, 33280 B), lS at +33280 (1 KB)
    __shared__ __align__(16) char smem[34304];
    short* PSbase = (short*)smem;
    float* OS = (float*)smem;
    float* lS = (float*)(smem + 33280);      // [8 waves][32 c]

    const int STEPS = 16;
    int blk = blockIdx.x;
    int b = blk & 7;
    int c0 = (blk >> 3) * 32;                // 64 c-tiles of 32 rows per b

    int tid = threadIdx.x;
    int w = tid >> 6, lane = tid & 63, ln = lane & 15, qd = lane >> 4;
    int g = w >> 2, wl = w & 3;              // kv-half group, wave-in-group
    int kv0 = g * 1024;
    short* PSg = PSbase + g * 4096;          // 2 buffers x 2048 shorts

    const short* qbase = Qa + (size_t)(b * 2048) * 128;
    const short* kbase = Ka + (size_t)(b * 2048 + kv0 + wl * 16 + ln) * 128 + qd * 8;
    const short* vbase = VaT + (size_t)(b * 256) * 2048;
    const float* mbase = maskadd + b * 2048 + kv0 + wl * 16 + qd * 4;

    // Q fragments: 2 c-tiles of 16 (B-operand layout), resident
    v8s qf[2][4];
#pragma unroll
    for (int ct = 0; ct < 2; ++ct) {
        const short* qp = qbase + (size_t)(c0 + ct * 16 + ln) * 128 + qd * 8;
#pragma unroll
        for (int kk = 0; kk < 4; ++kk) qf[ct][kk] = *(const v8s*)(qp + kk * 32);
    }

    v4f zero = {0.f, 0.f, 0.f, 0.f};
    v4f o[2][4];                            // [ct][dt]; d = wl*64+dt*16+ln
#pragma unroll
    for (int i = 0; i < 2; ++i)
#pragma unroll
        for (int j = 0; j < 4; ++j) o[i][j] = zero;
    float lacc[2] = {0.f, 0.f};

    // ---- prologue: kf(0)+mask(0) ----
    v8s kfA[4], kfB[4];
    float4 mkA, mkB;
#pragma unroll
    for (int kk = 0; kk < 4; ++kk) kfA[kk] = *(const v8s*)(kbase + kk * 32);
    mkA = *(const float4*)(mbase);

#define ATT_STEP(IT, KFC, MKC, KFN, MKN) do {                                  \
    int q0 = kv0 + (IT) * 64;                                                  \
    int itn = ((IT) + 1) & (STEPS - 1);                                        \
    {   /* prefetch NEXT step's K frags + mask into regs (5 VMEM) */           \
        const short* kp = kbase + (size_t)itn * 8192;                          \
        _Pragma("unroll")                                                      \
        for (int kk = 0; kk < 4; ++kk) KFN[kk] = *(const v8s*)(kp + kk * 32);  \
        MKN = *(const float4*)(mbase + itn * 64);                              \
    }                                                                          \
    short* PSc = PSg + ((IT) & 1) * 2048;                                      \
    int kvb = q0 + wl * 16 + qd * 4;                                           \
    _Pragma("unroll")                                                          \
    for (int ct = 0; ct < 2; ++ct) {                                           \
        v4f s = zero;                                                          \
        _Pragma("unroll")                                                      \
        for (int kk = 0; kk < 4; ++kk)                                         \
            s = __builtin_amdgcn_mfma_f32_16x16x32_bf16(KFC[kk], qf[ct][kk],   \
                                                        s, 0, 0, 0);           \
        int cg = c0 + ct * 16 + ln;                                            \
        v4s pw;                                                                \
        float ls = 0.f;                                                        \
        _Pragma("unroll")                                                      \
        for (int r = 0; r < 4; ++r) {                                          \
            float v = s[r] * SCL2 + (&MKC.x)[r];                               \
            if (kvb + r == cg) v = -__builtin_inff();                          \
            float p = exp2f(v);                                                \
            ls += p;                                                           \
            pw[r] = f2bf(p);                                                   \
        }                                                                      \
        lacc[ct] += ls;                                                        \
        int hs = ((wl * 2 + (qd >> 1)) ^ (ln & 7));                            \
        *(v4s*)(PSc + (ct * 16 + ln) * 64 + hs * 8 + (qd & 1) * 4) = pw;       \
    }                                                                          \
    /* V fragments direct from L2 (issued pre-barrier: latency hides) */       \
    v8s vf2[2][4];                                                             \
    {                                                                          \
        const short* vp = vbase + q0;                                          \
        _Pragma("unroll")                                                      \
        for (int kk2 = 0; kk2 < 2; ++kk2) {                                    \
            int xg = ((kk2 * 4 + qd) ^ (ln & 7)) << 3;                         \
            _Pragma("unroll")                                                  \
            for (int dt = 0; dt < 4; ++dt)                                     \
                vf2[kk2][dt] = *(const v8s*)(vp +                              \
                    (size_t)(wl * 64 + dt * 16 + ln) * 2048 + xg);             \
        }                                                                      \
    }                                                                          \
    asm volatile("s_waitcnt lgkmcnt(0)" ::: "memory");                         \
    __builtin_amdgcn_s_barrier();           /* P visible; WAR for IT-1 buf */  \
    __builtin_amdgcn_s_setprio(1);                                             \
    _Pragma("unroll")                                                          \
    for (int kk2 = 0; kk2 < 2; ++kk2) {                                        \
        v8s pf[2];                                                             \
        _Pragma("unroll")                                                      \
        for (int ct = 0; ct < 2; ++ct)                                         \
            pf[ct] = *(const v8s*)(PSc + (ct * 16 + ln) * 64 +                 \
                                   (((kk2 * 4 + qd) ^ (ln & 7)) << 3));        \
        _Pragma("unroll")                                                      \
        for (int ct = 0; ct < 2; ++ct)                                         \
            _Pragma("unroll")                                                  \
            for (int dt = 0; dt < 4; ++dt)                                     \
                o[ct][dt] = __builtin_amdgcn_mfma_f32_16x16x32_bf16(           \
                    pf[ct], vf2[kk2][dt], o[ct][dt], 0, 0, 0);                 \
    }                                                                          \
    __builtin_amdgcn_s_setprio(0);                                             \
} while (0)

#pragma unroll 1
    for (int it2 = 0; it2 < STEPS; it2 += 2) {
        ATT_STEP(it2, kfA, mkA, kfB, mkB);
        ATT_STEP(it2 + 1, kfB, mkB, kfA, mkA);
    }
#undef ATT_STEP

    // ---- epilogue: merge the two kv-halves ----
    __syncthreads();                         // PS dead; smem becomes OS/lS

    // l: reduce over qd in-wave, publish per-wave sums
#pragma unroll
    for (int ct = 0; ct < 2; ++ct) {
        float v = lacc[ct];
        v += __shfl_xor(v, 16);
        v += __shfl_xor(v, 32);
        if (qd == 0) lS[w * 32 + ct * 16 + ln] = v;
    }

    // group 1 dumps unnormalized O into LDS ([32 c][260 d-pad] f32)
    if (g == 1) {
#pragma unroll
        for (int ct = 0; ct < 2; ++ct)
#pragma unroll
            for (int r = 0; r < 4; ++r)
#pragma unroll
                for (int dt = 0; dt < 4; ++dt)
                    OS[(ct * 16 + qd * 4 + r) * 260 + wl * 64 + dt * 16 + ln] =
                        o[ct][dt][r];
    }
    __syncthreads();

    if (g == 0) {
#pragma unroll
        for (int ct = 0; ct < 2; ++ct) {
            float lv[4];
#pragma unroll
            for (int r = 0; r < 4; ++r) {
                float s = 0.f;
#pragma unroll
                for (int wv = 0; wv < 8; ++wv)
                    s += lS[wv * 32 + ct * 16 + qd * 4 + r];
                lv[r] = s;
            }
            int rowg = b * 2048 + c0 + ct * 16 + qd * 4;
#pragma unroll
            for (int r = 0; r < 4; ++r) {
                float inv = 1.f / lv[r];
#pragma unroll
                for (int dt = 0; dt < 4; ++dt) {
                    int col = wl * 64 + dt * 16 + ln;
                    float sum = o[ct][dt][r] +
                                OS[(ct * 16 + qd * 4 + r) * 260 + col];
                    out[(size_t)(rowg + r) * 256 + col] = sum * inv;
                }
            }
        }
    }
}

extern "C" void kernel_launch(void* const* d_in, const int* in_sizes, int n_in,
                              void* d_out, int out_size, void* d_ws, size_t ws_size,
                              hipStream_t stream) {
    const float* ctx  = (const float*)d_in[0];
    const float* qry  = (const float*)d_in[1];
    const float* win  = (const float*)d_in[2];
    const float* wmem = (const float*)d_in[3];
    const int* qmask  = (const int*)d_in[4];
    float* out = (float*)d_out;

    char* ws = (char*)d_ws;
    short* Qa      = (short*)(ws);                          // 4 MB
    short* Ka      = (short*)(ws + (4u << 20));             // 4 MB
    short* VaT     = (short*)(ws + (8u << 20));             // 8 MB (chunk-XOR swizzled)
    float* maskadd = (float*)(ws + (16u << 20));            // 64 KB

    k_pre<<<dim3(512), 256, 0, stream>>>(ctx, qry, win, wmem, qmask,
                                         Qa, Ka, VaT, maskadd);
    k_attn<<<dim3(512), 512, 0, stream>>>(Qa, Ka, VaT, maskadd, out);
}

// Round 13
// 146.068 us; speedup vs baseline: 2.3306x; 1.1202x over previous
//
#include <hip/hip_runtime.h>
#include <math.h>

typedef short v4s __attribute__((ext_vector_type(4)));
typedef short v8s __attribute__((ext_vector_type(8)));
typedef float v4f __attribute__((ext_vector_type(4)));

#define L2E 1.4426950408889634f
#define INV_SCALE 0.08838834764831845f       // 1/sqrt(128)
#define SCL2 (INV_SCALE * L2E)               // folded scale for exp2

static __device__ __forceinline__ short f2bf(float x) {
    union { float f; unsigned u; } c; c.f = x;
    unsigned u = c.u;
    unsigned r = (u + 0x7fffu + ((u >> 16) & 1u)) >> 16;  // RNE
    return (short)r;
}

typedef __attribute__((address_space(3))) void lds_vt;
typedef __attribute__((address_space(1))) const void gl_vt;
static __device__ __forceinline__ void gload_lds16(const void* g, void* l) {
    __builtin_amdgcn_global_load_lds((gl_vt*)g, (lds_vt*)l, 16, 0, 0);
}

// ---- P0 fused: 512 blocks. isel=0: ctx gemm->Qa. isel=1: qry gemm->Ka
// PLUS fused qry transpose->VaT + maskadd. VaT chunk-XOR swizzled
// (granule j of row d at position j^(d&7)).
// R13 edits vs R8 (k_attn untouched):
//  - W staged with float4 loads (was 128 scalar f32 loads/thread)
//  - Y stores bounced through dead WtS LDS -> 4x v8s coalesced stores
//    (was 32 scalar 2B stores/thread); stride 132 rows -> conflict-free.
__global__ __launch_bounds__(256) void k_pre(const float* __restrict__ ctx,
                                             const float* __restrict__ qry,
                                             const float* __restrict__ Win,
                                             const float* __restrict__ Wmem,
                                             const int* __restrict__ qmask,
                                             short* __restrict__ Qa,
                                             short* __restrict__ Ka,
                                             short* __restrict__ VaT,
                                             float* __restrict__ maskadd) {
    __shared__ __align__(16) short WtS[128 * 132];      // 33792 B
    __shared__ __align__(16) short Tt[256 * 72];        // 36864 B ([k][row64+pad])
    int x = blockIdx.x;
    int tid = threadIdx.x;
    int msel = x & 255, isel = x >> 8;
    const float* X = isel ? qry : ctx;
    const float* W = isel ? Wmem : Win;
    short* Y = isel ? Ka : Qa;

    int w = tid >> 6, lane = tid & 63;
    int ln = lane & 15, qd = lane >> 4;
    int m0 = msel * 64 + w * 16;
    v4f zero = {0.f, 0.f, 0.f, 0.f};
    v4f o[8];
#pragma unroll
    for (int i = 0; i < 8; ++i) o[i] = zero;

#pragma unroll 1
    for (int kh = 0; kh < 2; ++kh) {
        if (kh) __syncthreads();                        // protect WtS reuse
        // stage W k-half: 128 f x 128 k, float4 loads (coalesced)
#pragma unroll
        for (int i = 0; i < 16; ++i) {
            int id4 = i * 1024 + tid * 4;               // 4 consecutive fp
            int k = id4 >> 7, fp = id4 & 127;
            float4 wv = *(const float4*)(W + (size_t)(kh * 128 + k) * 128 + fp);
            WtS[(fp + 0) * 132 + k] = f2bf(wv.x);
            WtS[(fp + 1) * 132 + k] = f2bf(wv.y);
            WtS[(fp + 2) * 132 + k] = f2bf(wv.z);
            WtS[(fp + 3) * 132 + k] = f2bf(wv.w);
        }
        __syncthreads();
#pragma unroll
        for (int kk = 0; kk < 4; ++kk) {
            const float* xp = X + (size_t)(m0 + ln) * 256 + kh * 128 + kk * 32 + qd * 8;
            float4 x0 = *(const float4*)xp;
            float4 x1 = *(const float4*)(xp + 4);
            v8s a;
            a[0] = f2bf(x0.x); a[1] = f2bf(x0.y); a[2] = f2bf(x0.z); a[3] = f2bf(x0.w);
            a[4] = f2bf(x1.x); a[5] = f2bf(x1.y); a[6] = f2bf(x1.z); a[7] = f2bf(x1.w);
            if (isel) {                                  // fused transpose staging
#pragma unroll
                for (int si = 0; si < 8; ++si)
                    Tt[(kh * 128 + kk * 32 + qd * 8 + si) * 72 + (w * 16 + ln)] = a[si];
            }
#pragma unroll
            for (int nt = 0; nt < 8; ++nt) {
                v8s bfr = *(const v8s*)(WtS + (nt * 16 + ln) * 132 + kk * 32 + qd * 8);
                o[nt] = __builtin_amdgcn_mfma_f32_16x16x32_bf16(a, bfr, o[nt], 0, 0, 0);
            }
        }
    }

    // ---- ELU + Y store: bounce through WtS (dead after last MFMA) ----
    __syncthreads();                                     // all waves done w/ WtS
    {
        short* Yt = WtS + w * (16 * 132);                // wave-private 16x132
#pragma unroll
        for (int nt = 0; nt < 8; ++nt)
#pragma unroll
            for (int r = 0; r < 4; ++r) {
                float v = o[nt][r];
                v = v > 0.f ? v : 0.01f * (__expf(v) - 1.f);
                Yt[(qd * 4 + r) * 132 + nt * 16 + ln] = f2bf(v);
            }
        // wave-private RAW on LDS: compiler inserts lgkmcnt; then 16B stores
#pragma unroll
        for (int u = 0; u < 4; ++u) {
            int idx = u * 64 + lane;                     // 256 v8s units
            int row = idx >> 4, c8 = idx & 15;
            v8s yv = *(const v8s*)(Yt + row * 132 + c8 * 8);
            *(v8s*)(Y + (size_t)(m0 + row) * 128 + c8 * 8) = yv;
        }
    }

    if (isel) {
        __syncthreads();                                 // Tt complete
        int b2 = msel >> 5, q0 = (msel & 31) * 64;
        int dr = tid >> 3, j = tid & 7;
#pragma unroll
        for (int i = 0; i < 8; ++i) {
            int d = dr + i * 32;
            v8s vv = *(const v8s*)(Tt + d * 72 + j * 8);
            // chunk-XOR swizzle: granule j stored at position j^(d&7)
            *(v8s*)(VaT + ((size_t)(b2 * 256 + d)) * 2048 + q0 + ((j ^ (d & 7)) << 3)) = vv;
        }
        if (tid < 64) {
            int qq = b2 * 2048 + q0 + tid;
            maskadd[qq] = (qmask[qq] > 0) ? 0.f : -__builtin_inff();
        }
    }
}

// ------------- flash attention: IN-BLOCK kv-split, direct out -------------
// (verbatim R8 kernel: measured 54.4 us, passed; best of 6 structural
// variants R0-R12.) 256 blocks x 512 thr (8 waves = 2 groups of 4).
// Group g owns kv-half [g*1024, +1024): 16 steps of 64 kv, depth-2
// counted-vmcnt schedule per group (K/mask reg-prefetch 1 step ahead;
// V wave-private d-quarter dbuf via async global_load_lds; P per-group
// LDS chunk-XOR). End: group 1 dumps unnormalized O to LDS, group 0
// merges, normalizes, writes out. NO partials in HBM, NO combine kernel.
__global__ __launch_bounds__(512, 2) void k_attn(const short* __restrict__ Qa,
                                                 const short* __restrict__ Ka,
                                                 const short* __restrict__ VaT,
                                                 const float* __restrict__ maskadd,
                                                 float* __restrict__ out) {
    __shared__ __align__(16) short VaS[2][2][256 * 64];  // 128 KB [grp][buf]
    __shared__ __align__(16) short PS[2][64 * 64];       // 16 KB [grp] swizzled
    __shared__ float lS[8 * 64];                         // 2 KB

    const int STEPS = 16;
    int blk = blockIdx.x;
    int b = blk & 7;
    int c0 = (blk >> 3) * 64;

    int tid = threadIdx.x;
    int w = tid >> 6, lane = tid & 63, ln = lane & 15, qd = lane >> 4;
    int g = w >> 2, wl = w & 3;              // group, wave-in-group
    int kv0 = g * 1024;

    const short* qbase = Qa + (size_t)(b * 2048) * 128;
    const short* kbase = Ka + (size_t)(b * 2048 + kv0 + wl * 16 + ln) * 128 + qd * 8;
    const short* vbase = VaT + (size_t)(b * 256) * 2048;
    const float* mbase = maskadd + b * 2048 + kv0 + wl * 16 + qd * 4;

    // Q fragments for all 4 c-tiles (B-operand layout), resident
    v8s qf[4][4];
#pragma unroll
    for (int ct = 0; ct < 4; ++ct) {
        const short* qp = qbase + (size_t)(c0 + ct * 16 + ln) * 128 + qd * 8;
#pragma unroll
        for (int kk = 0; kk < 4; ++kk) qf[ct][kk] = *(const v8s*)(qp + kk * 32);
    }

    v4f zero = {0.f, 0.f, 0.f, 0.f};
    v4f o[4][4];                            // [ct][dt]
#pragma unroll
    for (int i = 0; i < 4; ++i)
#pragma unroll
        for (int j = 0; j < 4; ++j) o[i][j] = zero;
    float lacc[4] = {0.f, 0.f, 0.f, 0.f};

    // stage own d-quarter of V tile for kv window q0s into buf (wave-private)
    auto stageV = [&](int q0s, int buf) {
        short* base = &VaS[g][buf][0] + wl * 4096;   // rows wl*64..+63
#pragma unroll
        for (int j = 0; j < 8; ++j) {
            int U = (wl * 8 + j) * 64 + lane;        // 16B unit index
            int d = U >> 3, cc = U & 7;
            gload_lds16(vbase + (size_t)d * 2048 + q0s + cc * 8,
                        base + j * 512);
        }
    };

    // ---- prologue: stage0 | kf0 | stage1 (order pinned for in-order
    // vmcnt retirement arithmetic) ----
    v8s kfA[4], kfB[4];
    float4 mkA, mkB;
    stageV(kv0, 0);
    asm volatile("" ::: "memory");
#pragma unroll
    for (int kk = 0; kk < 4; ++kk) kfA[kk] = *(const v8s*)(kbase + kk * 32);
    mkA = *(const float4*)(mbase);
    asm volatile("" ::: "memory");
    stageV(kv0 + 64, 1);

#define ATT_STEP(IT, KFC, MKC, KFN, MKN) do {                                  \
    int q0 = kv0 + (IT) * 64;                                                  \
    int itn = ((IT) + 1) & (STEPS - 1);                                        \
    int itn2 = ((IT) + 2) & (STEPS - 1);                                       \
    {   /* prefetch NEXT step's K frags + mask into regs (5 VMEM) */           \
        const short* kp = kbase + (size_t)itn * 8192;                          \
        _Pragma("unroll")                                                      \
        for (int kk = 0; kk < 4; ++kk) KFN[kk] = *(const v8s*)(kp + kk * 32);  \
        MKN = *(const float4*)(mbase + itn * 64);                              \
    }                                                                          \
    /* retire stage(IT)+kf(IT); keep stage(IT+1)+kf(IT+1) = 13 in flight */    \
    asm volatile("s_waitcnt vmcnt(13)" ::: "memory");                          \
    int kvb = q0 + wl * 16 + qd * 4;                                           \
    _Pragma("unroll")                                                          \
    for (int ct = 0; ct < 4; ++ct) {                                           \
        v4f s = zero;                                                          \
        _Pragma("unroll")                                                      \
        for (int kk = 0; kk < 4; ++kk)                                         \
            s = __builtin_amdgcn_mfma_f32_16x16x32_bf16(KFC[kk], qf[ct][kk],   \
                                                        s, 0, 0, 0);           \
        int cg = c0 + ct * 16 + ln;                                            \
        v4s pw;                                                                \
        float ls = 0.f;                                                        \
        _Pragma("unroll")                                                      \
        for (int r = 0; r < 4; ++r) {                                          \
            float v = s[r] * SCL2 + (&MKC.x)[r];                               \
            if (kvb + r == cg) v = -__builtin_inff();                          \
            float p = exp2f(v);                                                \
            ls += p;                                                           \
            pw[r] = f2bf(p);                                                   \
        }                                                                      \
        lacc[ct] += ls;                                                        \
        int hs = ((wl * 2 + (qd >> 1)) ^ (ln & 7));                            \
        *(v4s*)(&PS[g][0] + (ct * 16 + ln) * 64 + hs * 8 + (qd & 1) * 4) = pw; \
    }                                                                          \
    asm volatile("s_waitcnt lgkmcnt(0)" ::: "memory");                         \
    __builtin_amdgcn_s_barrier();           /* P visible */                    \
    const short* vs = &VaS[g][(IT) & 1][0];                                    \
    __builtin_amdgcn_s_setprio(1);                                             \
    _Pragma("unroll")                                                          \
    for (int kk2 = 0; kk2 < 2; ++kk2) {                                        \
        v8s pf[4], vf[4];                                                      \
        _Pragma("unroll")                                                      \
        for (int ct = 0; ct < 4; ++ct)                                         \
            pf[ct] = *(const v8s*)(&PS[g][0] + (ct * 16 + ln) * 64 +           \
                                   (((kk2 * 4 + qd) ^ (ln & 7)) << 3));        \
        _Pragma("unroll")                                                      \
        for (int dt = 0; dt < 4; ++dt) {                                       \
            int d = wl * 64 + dt * 16 + ln;                                    \
            vf[dt] = *(const v8s*)(vs + d * 64 +                               \
                                   (((kk2 * 4 + qd) ^ (ln & 7)) << 3));        \
        }                                                                      \
        _Pragma("unroll")                                                      \
        for (int ct = 0; ct < 4; ++ct)                                         \
            _Pragma("unroll")                                                  \
            for (int dt = 0; dt < 4; ++dt)                                     \
                o[ct][dt] = __builtin_amdgcn_mfma_f32_16x16x32_bf16(           \
                    pf[ct], vf[dt], o[ct][dt], 0, 0, 0);                       \
    }                                                                          \
    __builtin_amdgcn_s_setprio(0);                                             \
    /* own P+V ds_reads drained -> safe to DMA-overwrite buf[(IT)&1] */        \
    asm volatile("s_waitcnt lgkmcnt(0)" ::: "memory");                         \
    stageV(kv0 + itn2 * 64, (IT) & 1);                                         \
    __builtin_amdgcn_s_barrier();           /* protect P for next write */     \
} while (0)

#pragma unroll 1
    for (int it2 = 0; it2 < STEPS; it2 += 2) {
        ATT_STEP(it2, kfA, mkA, kfB, mkB);
        ATT_STEP(it2 + 1, kfB, mkB, kfA, mkA);
    }
#undef ATT_STEP

    // ---- epilogue: drain trailing DMAs, then combine the two kv-halves ----
    asm volatile("s_waitcnt vmcnt(0)" ::: "memory");
    __syncthreads();

    // l: reduce over qd in-wave, publish per-wave sums
#pragma unroll
    for (int ct = 0; ct < 4; ++ct) {
        float v = lacc[ct];
        v += __shfl_xor(v, 16);
        v += __shfl_xor(v, 32);
        if (qd == 0) lS[w * 64 + ct * 16 + ln] = v;
    }

    // group 1 dumps unnormalized O into LDS (VaS reused; stride 260 pads
    // the 256-f32 row to kill the 4-way qd bank alias)
    float* OS = (float*)&VaS[0][0][0];       // [64 c][260 d-pad] f32, 66.6 KB
    if (g == 1) {
#pragma unroll
        for (int ct = 0; ct < 4; ++ct)
#pragma unroll
            for (int r = 0; r < 4; ++r)
#pragma unroll
                for (int dt = 0; dt < 4; ++dt)
                    OS[(ct * 16 + qd * 4 + r) * 260 + wl * 64 + dt * 16 + ln] =
                        o[ct][dt][r];
    }
    __syncthreads();

    if (g == 0) {
#pragma unroll
        for (int ct = 0; ct < 4; ++ct) {
            float lv[4];
#pragma unroll
            for (int r = 0; r < 4; ++r) {
                float s = 0.f;
#pragma unroll
                for (int wv = 0; wv < 8; ++wv)
                    s += lS[wv * 64 + ct * 16 + qd * 4 + r];
                lv[r] = s;
            }
            int rowg = b * 2048 + c0 + ct * 16 + qd * 4;
#pragma unroll
            for (int r = 0; r < 4; ++r) {
                float inv = 1.f / lv[r];
#pragma unroll
                for (int dt = 0; dt < 4; ++dt) {
                    int col = wl * 64 + dt * 16 + ln;
                    float sum = o[ct][dt][r] +
                                OS[(ct * 16 + qd * 4 + r) * 260 + col];
                    out[(size_t)(rowg + r) * 256 + col] = sum * inv;
                }
            }
        }
    }
}

extern "C" void kernel_launch(void* const* d_in, const int* in_sizes, int n_in,
                              void* d_out, int out_size, void* d_ws, size_t ws_size,
                              hipStream_t stream) {
    const float* ctx  = (const float*)d_in[0];
    const float* qry  = (const float*)d_in[1];
    const float* win  = (const float*)d_in[2];
    const float* wmem = (const float*)d_in[3];
    const int* qmask  = (const int*)d_in[4];
    float* out = (float*)d_out;

    char* ws = (char*)d_ws;
    short* Qa      = (short*)(ws);                          // 4 MB
    short* Ka      = (short*)(ws + (4u << 20));             // 4 MB
    short* VaT     = (short*)(ws + (8u << 20));             // 8 MB (chunk-XOR swizzled)
    float* maskadd = (float*)(ws + (16u << 20));            // 64 KB

    k_pre<<<dim3(512), 256, 0, stream>>>(ctx, qry, win, wmem, qmask,
                                         Qa, Ka, VaT, maskadd);
    k_attn<<<dim3(256), 512, 0, stream>>>(Qa, Ka, VaT, maskadd, out);
}